// Round 7
// baseline (213.959 us; speedup 1.0000x reference)
//
#include <hip/hip_runtime.h>

typedef unsigned short u16;
typedef __bf16 bf16x8 __attribute__((ext_vector_type(8)));
typedef float f32x4 __attribute__((ext_vector_type(4)));
typedef float f32x16 __attribute__((ext_vector_type(16)));
typedef unsigned u32x2v __attribute__((ext_vector_type(2)));

#define LOG2E 1.44269504088896340736f

__device__ __forceinline__ u16 f2bf(float f) {
  unsigned int u = __builtin_bit_cast(unsigned int, f);
  u += 0x7FFFu + ((u >> 16) & 1u);
  return (u16)(u >> 16);
}

// pack two f32 -> one u32 holding {lo16 = bf16(lo), hi16 = bf16(hi)} (pure C, no asm)
__device__ __forceinline__ unsigned pack2(float lo, float hi) {
  return (unsigned)f2bf(lo) | ((unsigned)f2bf(hi) << 16);
}

// permlane32 swap, T12 orientation: exchanges vdst's HIGH half with src's LOW half.
// after: a = {old_a[0:31], old_b[0:31]}, b = {old_a[32:63], old_b[32:63]}
__device__ __forceinline__ void pl32swap(unsigned& a, unsigned& b) {
  u32x2v r = __builtin_amdgcn_permlane32_swap(a, b, false, false);
  a = r[0]; b = r[1];
}

__device__ __forceinline__ void async16(const void* g, void* l) {
  __builtin_amdgcn_global_load_lds((void*)g, (void*)l, 16, 0, 0);
}

// ---------------- fused cast fp32 -> bf16 for x, qkv_w, out_w ----------------
__global__ void cast_all(const float* __restrict__ x, const float* __restrict__ w1,
                         const float* __restrict__ w2, u16* __restrict__ xb,
                         u16* __restrict__ w1b, u16* __restrict__ w2b) {
  int i = blockIdx.x * blockDim.x + threadIdx.x;
  const float* s; u16* d; int j;
  if (i < 1048576)      { s = x;  d = xb;  j = i; }
  else if (i < 1835008) { s = w1; d = w1b; j = i - 1048576; }
  else                  { s = w2; d = w2b; j = i - 1835008; }
  float4 v = ((const float4*)s)[j];
  union { u16 s4[4]; uint2 u; } o;
  o.s4[0] = f2bf(v.x); o.s4[1] = f2bf(v.y); o.s4[2] = f2bf(v.z); o.s4[3] = f2bf(v.w);
  ((uint2*)d)[j] = o.u;
}

// ---------------- bf16 NT GEMM: C[m][n] = sum_k A[m][k] * Bw[n][k] ----------------
// 128xBN tile, BK=32, 4 waves each 64x(BN/2). EPI 0: QKV scatter. EPI 1: fp32 out + bias.
template <int EPI, int BN>
__global__ __launch_bounds__(256)
void gemm_nt(const u16* __restrict__ A, const u16* __restrict__ Bw,
             int M, int N, int K, const float* __restrict__ bias,
             u16* __restrict__ qo, u16* __restrict__ ko, u16* __restrict__ vto,
             float* __restrict__ out, int ntn) {
  __shared__ __align__(16) u16 As[128 * 32];
  __shared__ __align__(16) u16 Bs[BN * 32];
  constexpr int JN = BN / 32;
  constexpr int NB = (BN * 4) / 256;
  const int tid = threadIdx.x;
  const int w = tid >> 6, lane = tid & 63;
  const int lr = lane & 15, lkb = lane >> 4;
  const int bx = blockIdx.x;
  const int mt = bx / ntn, nt = bx % ntn;
  const int m0 = mt * 128, n0 = nt * BN;
  const int wm = (w >> 1) * 64, wn = (w & 1) * (BN / 2);

  f32x4 acc[4][JN] = {};

  int srow[2], sgch[2];
#pragma unroll
  for (int i = 0; i < 2; ++i) {
    int cid = tid + i * 256;
    srow[i] = cid >> 2;
    sgch[i] = (cid & 3) ^ (srow[i] & 3);
  }

  for (int k0 = 0; k0 < K; k0 += 32) {
#pragma unroll
    for (int i = 0; i < 2; ++i) {
      char* la = (char*)As + (w * 64 + i * 256) * 16;
      async16(A + (size_t)(m0 + srow[i]) * K + k0 + sgch[i] * 8, la);
    }
#pragma unroll
    for (int i = 0; i < NB; ++i) {
      char* lb = (char*)Bs + (w * 64 + i * 256) * 16;
      async16(Bw + (size_t)(n0 + srow[i]) * K + k0 + sgch[i] * 8, lb);
    }
    __syncthreads();

    bf16x8 af[4], bfr[JN];
#pragma unroll
    for (int i = 0; i < 4; ++i) {
      int ra = wm + i * 16 + lr;
      af[i] = *(const bf16x8*)(As + ra * 32 + (lkb ^ (ra & 3)) * 8);
    }
#pragma unroll
    for (int j = 0; j < JN; ++j) {
      int rb = wn + j * 16 + lr;
      bfr[j] = *(const bf16x8*)(Bs + rb * 32 + (lkb ^ (rb & 3)) * 8);
    }
#pragma unroll
    for (int i = 0; i < 4; ++i)
#pragma unroll
      for (int j = 0; j < JN; ++j)
        acc[i][j] = __builtin_amdgcn_mfma_f32_16x16x32_bf16(af[i], bfr[j], acc[i][j], 0, 0, 0);
    __syncthreads();
  }

  if constexpr (EPI == 0) {
    const int which = n0 >> 10;
    const float qscale = (which == 0) ? 0.125f : 1.0f;
#pragma unroll
    for (int i = 0; i < 4; ++i) {
#pragma unroll
      for (int j = 0; j < JN; ++j) {
        int n = n0 + wn + j * 16 + lr;
        float bv = bias[n];
        int d = n & 1023, h = d >> 6, dd = d & 63;
#pragma unroll
        for (int r = 0; r < 4; ++r) {
          int m = m0 + wm + i * 16 + lkb * 4 + r;
          int b = m >> 11, s = m & 2047;
          int bh = b * 16 + h;
          u16 val = f2bf((acc[i][j][r] + bv) * qscale);
          if (which == 0)      qo[(bh * 2048 + s) * 64 + dd] = val;
          else if (which == 1) ko[(bh * 2048 + s) * 64 + dd] = val;
          else                 vto[(bh * 64 + dd) * 2048 + s] = val;
        }
      }
    }
  } else {
#pragma unroll
    for (int i = 0; i < 4; ++i)
#pragma unroll
      for (int j = 0; j < JN; ++j) {
        int n = n0 + wn + j * 16 + lr;
        float bv = bias[n];
#pragma unroll
        for (int r = 0; r < 4; ++r) {
          int m = m0 + wm + i * 16 + lkb * 4 + r;
          out[(size_t)m * N + n] = acc[i][j][r] + bv;
        }
      }
  }
}

// ---------------- causal flash attention, 32x32 MFMA, in-register softmax ----------
// Q,K: [BH=32][S=2048][64] bf16 (Q pre-scaled). Vt: [BH][64][S]. ctx: [B,S,1024] bf16.
// Block: 4 waves x 32 q = 128 q-rows. KV tile 64, double-buffered chunk-major LDS
// (conflict-free ds_read_b128 by construction). Grid 512: bid = h + 32*tt,
// qt = (tt<8)?15-tt:tt-8 pairs heavy+light supertiles; bid%8 = h%8 pins head to XCD.
__global__ __launch_bounds__(256, 2)
void flash_attn(const u16* __restrict__ Q, const u16* __restrict__ Kg,
                const u16* __restrict__ Vt, u16* __restrict__ ctx) {
  __shared__ __align__(16) u16 Kls[2][64 * 64];
  __shared__ __align__(16) u16 Vls[2][64 * 64];
  const int tid = threadIdx.x;
  const int w = tid >> 6, lane = tid & 63;
  const int l5 = lane & 31, hi = lane >> 5;
  const int bid = blockIdx.x;
  const int h = bid & 31;
  const int tt = bid >> 5;
  const int qt = (tt < 8) ? (15 - tt) : (tt - 8);
  const int q0w = qt * 128 + w * 32;   // wave's min q
  const int qrow = q0w + l5;           // lane's q row
  const u16* Qh = Q + (size_t)h * 2048 * 64;
  const u16* Kh = Kg + (size_t)h * 2048 * 64;
  const u16* Vh = Vt + (size_t)h * 2048 * 64;  // [64][2048]

  // Q B-frag: lane holds Q[qrow][ks*16 + hi*8 + e]
  bf16x8 bQ[4];
#pragma unroll
  for (int ks = 0; ks < 4; ++ks)
    bQ[ks] = *(const bf16x8*)(Qh + (size_t)qrow * 64 + ks * 16 + hi * 8);

  f32x16 accO[2] = {};      // O^T[d][q]: q=l5, d = g*32 + (r&3)+8*(r>>2)+4*hi
  float m_r = -1e30f, l_r = 0.f;

  // chunk-major staging: chunk ci = c*64 + r holds T[r][c*8..c*8+7]
  const int ra = tid & 63, ca = tid >> 6;        // issue A: chunks 0..255
  const int cb = ca + 4;                         // issue B: chunks 256..511 (row = ra)
  char* const ldA_K0 = (char*)&Kls[0][0] + (w * 64) * 16;
  char* const ldB_K0 = (char*)&Kls[0][0] + (w * 64 + 256) * 16;
  char* const ldA_V0 = (char*)&Vls[0][0] + (w * 64) * 16;
  char* const ldB_V0 = (char*)&Vls[0][0] + (w * 64 + 256) * 16;
  const int bufstep = 64 * 64 * 2;  // bytes between buf 0 and 1

  const int nkv = 2 * qt + 2;

  // prologue: stage tile 0 into buf 0
  async16(Kh + (size_t)ra * 64 + ca * 8, ldA_K0);
  async16(Kh + (size_t)ra * 64 + cb * 8, ldB_K0);
  async16(Vh + (size_t)ra * 2048 + ca * 8, ldA_V0);
  async16(Vh + (size_t)ra * 2048 + cb * 8, ldB_V0);
  __syncthreads();

  for (int t = 0; t < nkv; ++t) {
    const int cur = t & 1;
    const int kv0 = t * 64;
    if (t + 1 < nkv) {
      const int kv1 = kv0 + 64;
      const int bo = (cur ^ 1) * bufstep;
      async16(Kh + (size_t)(kv1 + ra) * 64 + ca * 8, ldA_K0 + bo);
      async16(Kh + (size_t)(kv1 + ra) * 64 + cb * 8, ldB_K0 + bo);
      async16(Vh + (size_t)ra * 2048 + kv1 + ca * 8, ldA_V0 + bo);
      async16(Vh + (size_t)ra * 2048 + kv1 + cb * 8, ldB_V0 + bo);
    }
    if (kv0 <= q0w + 31) {  // wave-uniform: skip fully-masked tiles
      const u16* Kb = &Kls[cur][0];
      const u16* Vb = &Vls[cur][0];

      // S^T = K * Q^T : sg[g] holds kv rows g*32 + rowmap, q col = l5
      f32x16 sg[2];
      __builtin_amdgcn_s_setprio(1);
#pragma unroll
      for (int g = 0; g < 2; ++g) {
        f32x16 z = {};
#pragma unroll
        for (int ks = 0; ks < 4; ++ks) {
          bf16x8 ka = *(const bf16x8*)(Kb + ((ks * 2 + hi) * 64 + g * 32 + l5) * 8);
          z = __builtin_amdgcn_mfma_f32_32x32x16_bf16(ka, bQ[ks], z, 0, 0, 0);
        }
        sg[g] = z;
      }
      __builtin_amdgcn_s_setprio(0);

      if (kv0 + 63 > q0w) {  // diagonal tile for this wave: elementwise causal mask
#pragma unroll
        for (int g = 0; g < 2; ++g)
#pragma unroll
          for (int r = 0; r < 16; ++r) {
            int kv = kv0 + g * 32 + (r & 3) + 8 * (r >> 2) + 4 * hi;
            if (kv > qrow) sg[g][r] = -1e30f;
          }
      }

      // row max: 32 in-lane values + partner-lane combine via permlane32
      float mt = sg[0][0];
#pragma unroll
      for (int r = 1; r < 16; ++r) mt = fmaxf(mt, sg[0][r]);
#pragma unroll
      for (int r = 0; r < 16; ++r) mt = fmaxf(mt, sg[1][r]);
      {
        unsigned a = __builtin_bit_cast(unsigned, mt), b = a;
        pl32swap(a, b);
        mt = fmaxf(__builtin_bit_cast(float, a), __builtin_bit_cast(float, b));
      }

      // defer-max rescale (THR=8)
      if (!__all(mt <= m_r + 8.0f)) {
        float mnew = fmaxf(m_r, mt);
        float sca = exp2f((m_r - mnew) * LOG2E);
        l_r *= sca;
        accO[0] *= sca;
        accO[1] *= sca;
        m_r = mnew;
      }
      const float mls = m_r * LOG2E;
      float rs = 0.f;
#pragma unroll
      for (int g = 0; g < 2; ++g)
#pragma unroll
        for (int r = 0; r < 16; ++r) {
          float p = exp2f(__builtin_fmaf(sg[g][r], LOG2E, -mls));
          sg[g][r] = p;
          rs += p;
        }
      {
        unsigned a = __builtin_bit_cast(unsigned, rs), b = a;
        pl32swap(a, b);
        rs = __builtin_bit_cast(float, a) + __builtin_bit_cast(float, b);
      }
      l_r += rs;

      // repack P -> B-frags: Pf[s] = P^T[kv = s*16 + hi*8 + e][q = l5]
      // T12 orientation: pl32swap(w0,w2) -> w0 = {w0_lo, w2_lo} (word0),
      //                                     w2 = {w0_hi, w2_hi} (word2)
      bf16x8 Pf[4];
#pragma unroll
      for (int s = 0; s < 4; ++s) {
        const int g = s >> 1, b8 = (s & 1) * 8;
        unsigned w0 = pack2(sg[g][b8 + 0], sg[g][b8 + 1]);
        unsigned w1 = pack2(sg[g][b8 + 2], sg[g][b8 + 3]);
        unsigned w2 = pack2(sg[g][b8 + 4], sg[g][b8 + 5]);
        unsigned w3 = pack2(sg[g][b8 + 6], sg[g][b8 + 7]);
        pl32swap(w0, w2);  // w0 -> e{0,1}, w2 -> e{4,5}
        pl32swap(w1, w3);  // w1 -> e{2,3}, w3 -> e{6,7}
        uint4 bb = {w0, w1, w2, w3};
        Pf[s] = __builtin_bit_cast(bf16x8, bb);
      }

      // O^T += V^T * P^T
      __builtin_amdgcn_s_setprio(1);
#pragma unroll
      for (int g = 0; g < 2; ++g)
#pragma unroll
        for (int s = 0; s < 4; ++s) {
          bf16x8 va = *(const bf16x8*)(Vb + ((s * 2 + hi) * 64 + g * 32 + l5) * 8);
          accO[g] = __builtin_amdgcn_mfma_f32_32x32x16_bf16(va, Pf[s], accO[g], 0, 0, 0);
        }
      __builtin_amdgcn_s_setprio(0);
    }
    __syncthreads();  // drains vmcnt(0): next tile staged
  }

  const float rl = 1.0f / l_r;
  const int b = h >> 4, hh = h & 15;
  const size_t base = ((size_t)(b * 2048 + qrow)) * 1024 + hh * 64;
#pragma unroll
  for (int g = 0; g < 2; ++g)
#pragma unroll
    for (int qd = 0; qd < 4; ++qd) {
      uint2 o;
      o.x = pack2(accO[g][qd * 4 + 0] * rl, accO[g][qd * 4 + 1] * rl);
      o.y = pack2(accO[g][qd * 4 + 2] * rl, accO[g][qd * 4 + 3] * rl);
      *(uint2*)(ctx + base + g * 32 + qd * 8 + hi * 4) = o;
    }
}

extern "C" void kernel_launch(void* const* d_in, const int* in_sizes, int n_in,
                              void* d_out, int out_size, void* d_ws, size_t ws_size,
                              hipStream_t stream) {
  (void)in_sizes; (void)n_in; (void)out_size; (void)ws_size;
  const float* x = (const float*)d_in[0];
  const float* qkv_w = (const float*)d_in[1];
  const float* qkv_b = (const float*)d_in[2];
  const float* out_w = (const float*)d_in[3];
  const float* out_b = (const float*)d_in[4];
  float* out = (float*)d_out;

  char* ws = (char*)d_ws;
  u16* xb   = (u16*)(ws);                 // 8 MiB
  u16* wqkv = (u16*)(ws + 8388608);       // 6 MiB
  u16* wout = (u16*)(ws + 14680064);      // 2 MiB
  u16* Qb   = (u16*)(ws + 16777216);      // 8 MiB  [BH][S][64]
  u16* Kb   = (u16*)(ws + 25165824);      // 8 MiB  [BH][S][64]
  u16* Vtb  = (u16*)(ws + 33554432);      // 8 MiB  [BH][64][S]
  u16* ctx  = (u16*)(ws + 41943040);      // 8 MiB  [B,S,1024]

  cast_all<<<8192, 256, 0, stream>>>(x, qkv_w, out_w, xb, wqkv, wout);

  gemm_nt<0, 128><<<768, 256, 0, stream>>>(xb, wqkv, 4096, 3072, 1024, qkv_b,
                                           Qb, Kb, Vtb, nullptr, 24);
  flash_attn<<<512, 256, 0, stream>>>(Qb, Kb, Vtb, ctx);
  gemm_nt<1, 64><<<512, 256, 0, stream>>>(ctx, wout, 4096, 1024, 1024, out_b,
                                          nullptr, nullptr, nullptr, out, 16);
}

// Round 9
// 211.904 us; speedup vs baseline: 1.0097x; 1.0097x over previous
//
#include <hip/hip_runtime.h>

typedef unsigned short u16;
typedef __bf16 bf16x8 __attribute__((ext_vector_type(8)));
typedef float f32x4 __attribute__((ext_vector_type(4)));
typedef float f32x16 __attribute__((ext_vector_type(16)));
typedef unsigned u32x2v __attribute__((ext_vector_type(2)));

#define LOG2E 1.44269504088896340736f

__device__ __forceinline__ u16 f2bf(float f) {
  unsigned int u = __builtin_bit_cast(unsigned int, f);
  u += 0x7FFFu + ((u >> 16) & 1u);
  return (u16)(u >> 16);
}

// hw packed cvt: {lo16=bf16(lo), hi16=bf16(hi)}. Safe: consumers are builtins
// (compiler-visible dep), hazard handling on the permlane side is automatic.
__device__ __forceinline__ unsigned cvtpk_bf16(float lo, float hi) {
  unsigned r;
  asm("v_cvt_pk_bf16_f32 %0, %1, %2" : "=v"(r) : "v"(lo), "v"(hi));
  return r;
}

// permlane32 swap, T12 orientation (verified r7):
// after: a = {old_a[0:31], old_b[0:31]}, b = {old_a[32:63], old_b[32:63]}
__device__ __forceinline__ void pl32swap(unsigned& a, unsigned& b) {
  u32x2v r = __builtin_amdgcn_permlane32_swap(a, b, false, false);
  a = r[0]; b = r[1];
}

__device__ __forceinline__ void async16(const void* g, void* l) {
  __builtin_amdgcn_global_load_lds((void*)g, (void*)l, 16, 0, 0);
}

// ---------------- fused cast fp32 -> bf16 for x, qkv_w, out_w ----------------
__global__ void cast_all(const float* __restrict__ x, const float* __restrict__ w1,
                         const float* __restrict__ w2, u16* __restrict__ xb,
                         u16* __restrict__ w1b, u16* __restrict__ w2b) {
  int i = blockIdx.x * blockDim.x + threadIdx.x;
  const float* s; u16* d; int j;
  if (i < 1048576)      { s = x;  d = xb;  j = i; }
  else if (i < 1835008) { s = w1; d = w1b; j = i - 1048576; }
  else                  { s = w2; d = w2b; j = i - 1835008; }
  float4 v = ((const float4*)s)[j];
  union { u16 s4[4]; uint2 u; } o;
  o.s4[0] = f2bf(v.x); o.s4[1] = f2bf(v.y); o.s4[2] = f2bf(v.z); o.s4[3] = f2bf(v.w);
  ((uint2*)d)[j] = o.u;
}

// ---------------- bf16 NT GEMM: C[m][n] = sum_k A[m][k] * Bw[n][k] ----------------
template <int EPI, int BN>
__global__ __launch_bounds__(256)
void gemm_nt(const u16* __restrict__ A, const u16* __restrict__ Bw,
             int M, int N, int K, const float* __restrict__ bias,
             u16* __restrict__ qo, u16* __restrict__ ko, u16* __restrict__ vto,
             float* __restrict__ out, int ntn) {
  __shared__ __align__(16) u16 As[128 * 32];
  __shared__ __align__(16) u16 Bs[BN * 32];
  constexpr int JN = BN / 32;
  constexpr int NB = (BN * 4) / 256;
  const int tid = threadIdx.x;
  const int w = tid >> 6, lane = tid & 63;
  const int lr = lane & 15, lkb = lane >> 4;
  const int bx = blockIdx.x;
  const int mt = bx / ntn, nt = bx % ntn;
  const int m0 = mt * 128, n0 = nt * BN;
  const int wm = (w >> 1) * 64, wn = (w & 1) * (BN / 2);

  f32x4 acc[4][JN] = {};

  int srow[2], sgch[2];
#pragma unroll
  for (int i = 0; i < 2; ++i) {
    int cid = tid + i * 256;
    srow[i] = cid >> 2;
    sgch[i] = (cid & 3) ^ (srow[i] & 3);
  }

  for (int k0 = 0; k0 < K; k0 += 32) {
#pragma unroll
    for (int i = 0; i < 2; ++i) {
      char* la = (char*)As + (w * 64 + i * 256) * 16;
      async16(A + (size_t)(m0 + srow[i]) * K + k0 + sgch[i] * 8, la);
    }
#pragma unroll
    for (int i = 0; i < NB; ++i) {
      char* lb = (char*)Bs + (w * 64 + i * 256) * 16;
      async16(Bw + (size_t)(n0 + srow[i]) * K + k0 + sgch[i] * 8, lb);
    }
    __syncthreads();

    bf16x8 af[4], bfr[JN];
#pragma unroll
    for (int i = 0; i < 4; ++i) {
      int ra = wm + i * 16 + lr;
      af[i] = *(const bf16x8*)(As + ra * 32 + (lkb ^ (ra & 3)) * 8);
    }
#pragma unroll
    for (int j = 0; j < JN; ++j) {
      int rb = wn + j * 16 + lr;
      bfr[j] = *(const bf16x8*)(Bs + rb * 32 + (lkb ^ (rb & 3)) * 8);
    }
#pragma unroll
    for (int i = 0; i < 4; ++i)
#pragma unroll
      for (int j = 0; j < JN; ++j)
        acc[i][j] = __builtin_amdgcn_mfma_f32_16x16x32_bf16(af[i], bfr[j], acc[i][j], 0, 0, 0);
    __syncthreads();
  }

  if constexpr (EPI == 0) {
    const int which = n0 >> 10;
    const float qscale = (which == 0) ? 0.125f : 1.0f;
#pragma unroll
    for (int i = 0; i < 4; ++i) {
#pragma unroll
      for (int j = 0; j < JN; ++j) {
        int n = n0 + wn + j * 16 + lr;
        float bv = bias[n];
        int d = n & 1023, h = d >> 6, dd = d & 63;
#pragma unroll
        for (int r = 0; r < 4; ++r) {
          int m = m0 + wm + i * 16 + lkb * 4 + r;
          int b = m >> 11, s = m & 2047;
          int bh = b * 16 + h;
          u16 val = f2bf((acc[i][j][r] + bv) * qscale);
          if (which == 0)      qo[(bh * 2048 + s) * 64 + dd] = val;
          else if (which == 1) ko[(bh * 2048 + s) * 64 + dd] = val;
          else                 vto[(bh * 64 + dd) * 2048 + s] = val;
        }
      }
    }
  } else {
#pragma unroll
    for (int i = 0; i < 4; ++i)
#pragma unroll
      for (int j = 0; j < JN; ++j) {
        int n = n0 + wn + j * 16 + lr;
        float bv = bias[n];
#pragma unroll
        for (int r = 0; r < 4; ++r) {
          int m = m0 + wm + i * 16 + lkb * 4 + r;
          out[(size_t)m * N + n] = acc[i][j][r] + bv;
        }
      }
  }
}

// ---------------- causal flash attention, 32x32 MFMA, counted-vmcnt pipeline -------
// Q,K: [BH=32][S=2048][64] bf16 (Q pre-scaled). Vt: [BH][64][S]. ctx: [B,S,1024] bf16.
// 4 waves x 32 q = 128 q/block. KV tile 64; 3 LDS buffers, prefetch 2 tiles ahead,
// s_waitcnt vmcnt(8) + raw s_barrier (no vmcnt(0) drain in the main loop).
__global__ __launch_bounds__(256, 2)
void flash_attn(const u16* __restrict__ Q, const u16* __restrict__ Kg,
                const u16* __restrict__ Vt, u16* __restrict__ ctx) {
  __shared__ __align__(16) u16 Kls[3][64 * 64];
  __shared__ __align__(16) u16 Vls[3][64 * 64];
  const int tid = threadIdx.x;
  const int w = tid >> 6, lane = tid & 63;
  const int l5 = lane & 31, hi = lane >> 5;
  const int bid = blockIdx.x;
  const int h = bid & 31;
  const int tt = bid >> 5;
  const int qt = (tt < 8) ? (15 - tt) : (tt - 8);
  const int q0w = qt * 128 + w * 32;
  const int qrow = q0w + l5;
  const u16* Qh = Q + (size_t)h * 2048 * 64;
  const u16* Kh = Kg + (size_t)h * 2048 * 64;
  const u16* Vh = Vt + (size_t)h * 2048 * 64;  // [64][2048]

  bf16x8 bQ[4];
#pragma unroll
  for (int ks = 0; ks < 4; ++ks)
    bQ[ks] = *(const bf16x8*)(Qh + (size_t)qrow * 64 + ks * 16 + hi * 8);

  f32x16 accO[2] = {};
  float m_r = -1e30f, l_r = 0.f;

  // chunk-major staging: chunk ci = c*64 + r holds T[r][c*8..c*8+7]
  const int ra = tid & 63, ca = tid >> 6, cb = ca + 4;
  char* const kq = (char*)&Kls[0][0] + w * 1024;   // wave's K quarter in buf 0
  char* const vq = (char*)&Vls[0][0] + w * 1024;

#define STAGE(tile, bi) do {                                            \
    const int _bo = (bi) * 8192;                                        \
    async16(Kh + (size_t)((tile) * 64 + ra) * 64 + ca * 8, kq + _bo);   \
    async16(Kh + (size_t)((tile) * 64 + ra) * 64 + cb * 8, kq + _bo + 4096); \
    async16(Vh + (size_t)ra * 2048 + (tile) * 64 + ca * 8, vq + _bo);   \
    async16(Vh + (size_t)ra * 2048 + (tile) * 64 + cb * 8, vq + _bo + 4096); \
  } while (0)

  const int nkv = 2 * qt + 2;
  STAGE(0, 0);
  STAGE(1, 1);

  int bcur = 0;  // t % 3
  for (int t = 0; t < nkv; ++t) {
    const int rem = nkv - t;
    if (rem > 2) {
      int b2 = bcur + 2; if (b2 >= 3) b2 -= 3;
      STAGE(t + 2, b2);
      asm volatile("s_waitcnt vmcnt(8)" ::: "memory");
    } else if (rem > 1) {
      asm volatile("s_waitcnt vmcnt(4)" ::: "memory");
    } else {
      asm volatile("s_waitcnt vmcnt(0)" ::: "memory");
    }
    __builtin_amdgcn_s_barrier();          // tile t published by all waves
    __builtin_amdgcn_sched_barrier(0);

    const int kv0 = t * 64;
    if (kv0 <= q0w + 31) {                 // wave-uniform skip of fully-masked tiles
      const u16* Kb = &Kls[bcur][0];
      const u16* Vb = &Vls[bcur][0];

      // S^T = K * Q^T
      f32x16 sg[2];
      __builtin_amdgcn_s_setprio(1);
#pragma unroll
      for (int g = 0; g < 2; ++g) {
        f32x16 z = {};
#pragma unroll
        for (int ks = 0; ks < 4; ++ks) {
          bf16x8 ka = *(const bf16x8*)(Kb + ((ks * 2 + hi) * 64 + g * 32 + l5) * 8);
          z = __builtin_amdgcn_mfma_f32_32x32x16_bf16(ka, bQ[ks], z, 0, 0, 0);
        }
        sg[g] = z;
      }
      __builtin_amdgcn_s_setprio(0);

      if (kv0 + 63 > q0w) {                // diagonal tile: elementwise causal mask
#pragma unroll
        for (int g = 0; g < 2; ++g)
#pragma unroll
          for (int r = 0; r < 16; ++r) {
            int kv = kv0 + g * 32 + (r & 3) + 8 * (r >> 2) + 4 * hi;
            if (kv > qrow) sg[g][r] = -1e30f;
          }
      }

      // tree max (depth 5) + partner-lane combine
      float t8[8];
#pragma unroll
      for (int i = 0; i < 8; ++i)
        t8[i] = fmaxf(fmaxf(sg[0][i], sg[0][i + 8]), fmaxf(sg[1][i], sg[1][i + 8]));
      float t4a = fmaxf(t8[0], t8[4]), t4b = fmaxf(t8[1], t8[5]);
      float t4c = fmaxf(t8[2], t8[6]), t4d = fmaxf(t8[3], t8[7]);
      float mt = fmaxf(fmaxf(t4a, t4b), fmaxf(t4c, t4d));
      {
        unsigned a = __builtin_bit_cast(unsigned, mt), b = a;
        pl32swap(a, b);
        mt = fmaxf(__builtin_bit_cast(float, a), __builtin_bit_cast(float, b));
      }

      // defer-max rescale (THR=8)
      if (!__all(mt <= m_r + 8.0f)) {
        float mnew = fmaxf(m_r, mt);
        float sca = exp2f((m_r - mnew) * LOG2E);
        l_r *= sca;
        accO[0] *= sca;
        accO[1] *= sca;
        m_r = mnew;
      }
      const float mls = m_r * LOG2E;
#pragma unroll
      for (int g = 0; g < 2; ++g)
#pragma unroll
        for (int r = 0; r < 16; ++r)
          sg[g][r] = exp2f(__builtin_fmaf(sg[g][r], LOG2E, -mls));

      // tree sum (depth 5) + partner-lane combine
      float s8[8];
#pragma unroll
      for (int i = 0; i < 8; ++i)
        s8[i] = (sg[0][i] + sg[0][i + 8]) + (sg[1][i] + sg[1][i + 8]);
      float s4a = s8[0] + s8[4], s4b = s8[1] + s8[5];
      float s4c = s8[2] + s8[6], s4d = s8[3] + s8[7];
      float rs = (s4a + s4b) + (s4c + s4d);
      {
        unsigned a = __builtin_bit_cast(unsigned, rs), b = a;
        pl32swap(a, b);
        rs = __builtin_bit_cast(float, a) + __builtin_bit_cast(float, b);
      }
      l_r += rs;

      // repack P -> B-frags (T12): Pf[s] = P^T[kv = s*16 + hi*8 + e][q = l5]
      bf16x8 Pf[4];
#pragma unroll
      for (int s = 0; s < 4; ++s) {
        const int g = s >> 1, b8 = (s & 1) * 8;
        unsigned w0 = cvtpk_bf16(sg[g][b8 + 0], sg[g][b8 + 1]);
        unsigned w1 = cvtpk_bf16(sg[g][b8 + 2], sg[g][b8 + 3]);
        unsigned w2 = cvtpk_bf16(sg[g][b8 + 4], sg[g][b8 + 5]);
        unsigned w3 = cvtpk_bf16(sg[g][b8 + 6], sg[g][b8 + 7]);
        pl32swap(w0, w2);
        pl32swap(w1, w3);
        uint4 bb = {w0, w1, w2, w3};
        Pf[s] = __builtin_bit_cast(bf16x8, bb);
      }

      // O^T += V^T * P^T
      __builtin_amdgcn_s_setprio(1);
#pragma unroll
      for (int g = 0; g < 2; ++g)
#pragma unroll
        for (int s = 0; s < 4; ++s) {
          bf16x8 va = *(const bf16x8*)(Vb + ((s * 2 + hi) * 64 + g * 32 + l5) * 8);
          accO[g] = __builtin_amdgcn_mfma_f32_32x32x16_bf16(va, Pf[s], accO[g], 0, 0, 0);
        }
      __builtin_amdgcn_s_setprio(0);
    }
    __builtin_amdgcn_s_barrier();          // tile t consumed by all waves
    if (++bcur == 3) bcur = 0;
  }
#undef STAGE

  const float rl = 1.0f / l_r;
  const int b = h >> 4, hh = h & 15;
  const size_t base = ((size_t)(b * 2048 + qrow)) * 1024 + hh * 64;
#pragma unroll
  for (int g = 0; g < 2; ++g)
#pragma unroll
    for (int qd = 0; qd < 4; ++qd) {
      uint2 o;
      o.x = cvtpk_bf16(accO[g][qd * 4 + 0] * rl, accO[g][qd * 4 + 1] * rl);
      o.y = cvtpk_bf16(accO[g][qd * 4 + 2] * rl, accO[g][qd * 4 + 3] * rl);
      *(uint2*)(ctx + base + g * 32 + qd * 8 + hi * 4) = o;
    }
}

extern "C" void kernel_launch(void* const* d_in, const int* in_sizes, int n_in,
                              void* d_out, int out_size, void* d_ws, size_t ws_size,
                              hipStream_t stream) {
  (void)in_sizes; (void)n_in; (void)out_size; (void)ws_size;
  const float* x = (const float*)d_in[0];
  const float* qkv_w = (const float*)d_in[1];
  const float* qkv_b = (const float*)d_in[2];
  const float* out_w = (const float*)d_in[3];
  const float* out_b = (const float*)d_in[4];
  float* out = (float*)d_out;

  char* ws = (char*)d_ws;
  u16* xb   = (u16*)(ws);                 // 8 MiB
  u16* wqkv = (u16*)(ws + 8388608);       // 6 MiB
  u16* wout = (u16*)(ws + 14680064);      // 2 MiB
  u16* Qb   = (u16*)(ws + 16777216);      // 8 MiB  [BH][S][64]
  u16* Kb   = (u16*)(ws + 25165824);      // 8 MiB  [BH][S][64]
  u16* Vtb  = (u16*)(ws + 33554432);      // 8 MiB  [BH][64][S]
  u16* ctx  = (u16*)(ws + 41943040);      // 8 MiB  [B,S,1024]

  cast_all<<<8192, 256, 0, stream>>>(x, qkv_w, out_w, xb, wqkv, wout);

  gemm_nt<0, 128><<<768, 256, 0, stream>>>(xb, wqkv, 4096, 3072, 1024, qkv_b,
                                           Qb, Kb, Vtb, nullptr, 24);
  flash_attn<<<512, 256, 0, stream>>>(Qb, Kb, Vtb, ctx);
  gemm_nt<1, 64><<<512, 256, 0, stream>>>(ctx, wout, 4096, 1024, 1024, out_b,
                                          nullptr, nullptr, nullptr, out, 16);
}